// Round 12
// baseline (116.151 us; speedup 1.0000x reference)
//
#include <hip/hip_runtime.h>

typedef float f32x4 __attribute__((ext_vector_type(4)));
typedef __bf16 bf16x8 __attribute__((ext_vector_type(8)));

#define D_MODEL 1024
#define SEQ     2048
#define NB      2
#define NH      16
#define DK      64

__device__ __forceinline__ unsigned short f2bf(float f) {
    union { float f; unsigned int u; } un; un.f = f;
    unsigned int r = un.u + 0x7fffu + ((un.u >> 16) & 1u);
    return (unsigned short)(r >> 16);
}

__device__ __forceinline__ unsigned cvtpk(float lo, float hi) {
    unsigned r;
    asm("v_cvt_pk_bf16_f32 %0, %1, %2" : "=v"(r) : "v"(lo), "v"(hi));
    return r;
}

__device__ __forceinline__ void gload16(const void* g, void* l) {
    __builtin_amdgcn_global_load_lds((__attribute__((address_space(1))) void*)g,
                                     (__attribute__((address_space(3))) void*)l,
                                     16, 0, 0);
}

// ---------------------------------------------------------------------------
// fused fp32 -> bf16 casts for x and the 4 weights + RoPE cos/sin table
// ---------------------------------------------------------------------------
__global__ __launch_bounds__(256) void cast5(
    const float* __restrict__ x,  const float* __restrict__ wq,
    const float* __restrict__ wk, const float* __restrict__ wv,
    const float* __restrict__ wo,
    unsigned short* __restrict__ xb,  unsigned short* __restrict__ wqb,
    unsigned short* __restrict__ wkb, unsigned short* __restrict__ wvb,
    unsigned short* __restrict__ wob, float2* __restrict__ tab)
{
    if (blockIdx.y == 5) {  // RoPE table: [ss][p] -> (cos, sin), p = d/2 index
        int idx = blockIdx.x * 256 + threadIdx.x;
        if (idx < SEQ * 32) {
            int ss = idx >> 5, p = idx & 31;
            float freq = exp2f(-0.41524101186f * (float)p);  // 10000^(-p/32)
            float sn, cs;
            sincosf((float)ss * freq, &sn, &cs);
            tab[idx] = make_float2(cs, sn);
        }
        return;
    }
    const float* src; unsigned short* dst; int n8;
    switch (blockIdx.y) {
        case 0:  src = x;  dst = xb;  n8 = (NB*SEQ*D_MODEL)/8; break;
        case 1:  src = wq; dst = wqb; n8 = (D_MODEL*D_MODEL)/8; break;
        case 2:  src = wk; dst = wkb; n8 = (D_MODEL*D_MODEL)/8; break;
        case 3:  src = wv; dst = wvb; n8 = (D_MODEL*D_MODEL)/8; break;
        default: src = wo; dst = wob; n8 = (D_MODEL*D_MODEL)/8; break;
    }
    int stride = gridDim.x * blockDim.x;
    for (int i = blockIdx.x * blockDim.x + threadIdx.x; i < n8; i += stride) {
        const float4* p = (const float4*)src + (size_t)i * 2;
        float4 a = p[0], b = p[1];
        union { unsigned short h[8]; uint4 v; } u;
        u.h[0] = f2bf(a.x); u.h[1] = f2bf(a.y); u.h[2] = f2bf(a.z); u.h[3] = f2bf(a.w);
        u.h[4] = f2bf(b.x); u.h[5] = f2bf(b.y); u.h[6] = f2bf(b.z); u.h[7] = f2bf(b.w);
        ((uint4*)dst)[i] = u.v;
    }
}

// ---------------------------------------------------------------------------
// GEMM  C[M][1024] = A[M][K](bf16) * B[1024][K]^T (bf16, weights are [out][in])
// Triple-buffered LDS + 2-deep prefetch + counted vmcnt + A-panel XCD
// clustering. Conflict-reduced LDS layout (R11): global 16B unit u of
// tile-row r lives at slot (u + (r>>1)) & 3 -> fragment reads are 2-way
// bank-aliased (free) instead of 8-way. Both-sides: stage pre-rotates the
// per-lane GLOBAL source; LDS dest linear (gload_lds constraint); reads
// apply the same rotation.
// MODE 0 (BM=64, BN=128): plain fp32 write to outF
// MODE 1 (BM=BN=128): QKV fused, RoPE epilogue via LDS.
// ---------------------------------------------------------------------------
template <int MODE, int BM, int BN>
__global__ __launch_bounds__(256) void gemm_bt(
    const unsigned short* __restrict__ A,
    const unsigned short* __restrict__ B0,
    const unsigned short* __restrict__ B1,
    const unsigned short* __restrict__ B2,
    float* __restrict__ outF,
    unsigned short* __restrict__ Qh,
    unsigned short* __restrict__ Kh,
    unsigned short* __restrict__ Vt,
    const float2* __restrict__ tab,
    int M, int K)
{
    constexpr int PER_STAGE = (BM + BN) / 64;
    constexpr int WM = BM / 2, WN = BN / 2;
    constexpr int FM = WM / 16, FN = WN / 16;
    __shared__ __align__(16) unsigned short SM[3 * (BM + BN) * 32];

    const int lane = threadIdx.x & 63;
    const int wid  = threadIdx.x >> 6;
    const int l15 = lane & 15, lhi = lane >> 4;

    // ---- block swizzle decode: L = (y&7) + 8*(x + 8*(y>>3) + 32*z) ----
    const int L  = blockIdx.x;
    const int yl = L & 7;
    const int t  = L >> 3;
    const int bx = t & 7;
    const int t2 = t >> 3;
    int y, z;
    if constexpr (MODE == 1) { y = ((t2 & 3) << 3) | yl; z = t2 >> 2; }
    else                     { y = (t2 << 3) | yl;       z = 0;       }
    const int m0 = y * BM;
    const int n0 = bx * BN;
    const unsigned short* B = (z == 0) ? B0 : (z == 1) ? B1 : B2;
    const int waveM = (wid >> 1) * WM;
    const int waveN = (wid & 1) * WN;

    f32x4 acc[FM][FN];
    f32x4 zero = {0.f, 0.f, 0.f, 0.f};
#pragma unroll
    for (int m = 0; m < FM; ++m)
#pragma unroll
        for (int n = 0; n < FN; ++n) acc[m][n] = zero;

    const int lrow = lane >> 2;       // row within 16-row staging chunk
    const int uslot = lane & 3;       // dest 16B slot within row

    auto STAGE = [&](int buf, int k0) {
        unsigned short* as = SM + buf * (BM + BN) * 32;
        unsigned short* bs = as + BM * 32;
#pragma unroll
        for (int q = 0; q < BM / 64; ++q) {
            int rbase = wid * (BM / 4) + q * 16;
            int r = rbase + lrow;
            int ug = (uslot - (r >> 1)) & 3;   // rotated global source unit
            gload16(A + (size_t)(m0 + r) * K + k0 + ug * 8,
                    (char*)as + rbase * 64);
        }
#pragma unroll
        for (int q = 0; q < BN / 64; ++q) {
            int rbase = wid * (BN / 4) + q * 16;
            int r = rbase + lrow;
            int ug = (uslot - (r >> 1)) & 3;
            gload16(B + (size_t)(n0 + r) * K + k0 + ug * 8,
                    (char*)bs + rbase * 64);
        }
    };

    const int NK = K >> 5;            // 32 K-steps
    STAGE(0, 0);
    STAGE(1, 32);

    for (int k = 0; k < NK; ++k) {
        if (k < NK - 1) {
            if constexpr (PER_STAGE == 4) asm volatile("s_waitcnt vmcnt(4)" ::: "memory");
            else                          asm volatile("s_waitcnt vmcnt(3)" ::: "memory");
        } else {
            asm volatile("s_waitcnt vmcnt(0)" ::: "memory");
        }
        __builtin_amdgcn_s_barrier();
        __builtin_amdgcn_sched_barrier(0);
        if (k + 2 < NK) STAGE((k + 2) % 3, (k + 2) << 5);

        const unsigned short* as = SM + (k % 3) * (BM + BN) * 32;
        const unsigned short* bs = as + BM * 32;
        bf16x8 af[FM], bfr[FN];
#pragma unroll
        for (int m = 0; m < FM; ++m) {
            int ra = waveM + m * 16 + l15;
            af[m] = *(const bf16x8*)(as + ra * 32 + (((lhi + (ra >> 1)) & 3) << 3));
        }
#pragma unroll
        for (int n = 0; n < FN; ++n) {
            int rb = waveN + n * 16 + l15;
            bfr[n] = *(const bf16x8*)(bs + rb * 32 + (((lhi + (rb >> 1)) & 3) << 3));
        }
        __builtin_amdgcn_s_setprio(1);
#pragma unroll
        for (int m = 0; m < FM; ++m)
#pragma unroll
            for (int n = 0; n < FN; ++n)
                acc[m][n] = __builtin_amdgcn_mfma_f32_16x16x32_bf16(af[m], bfr[n], acc[m][n], 0, 0, 0);
        __builtin_amdgcn_s_setprio(0);
    }

    if constexpr (MODE == 0) {
#pragma unroll
        for (int n = 0; n < FN; ++n) {
            int col = n0 + waveN + n * 16 + l15;
#pragma unroll
            for (int m = 0; m < FM; ++m) {
                int rowb = m0 + waveM + m * 16 + (lhi << 2);
#pragma unroll
                for (int r = 0; r < 4; ++r)
                    outF[(size_t)(rowb + r) * D_MODEL + col] = acc[m][n][r];
            }
        }
    } else {
        __syncthreads();  // all waves done with stage buffers before aliasing
        unsigned short* Ct = ((unsigned short*)SM) + wid * 4608;  // 64x72/wave
        const int colg0 = n0 + waveN;
        const int hh    = (colg0 >> 6) & (NH - 1);
        const int rowg0 = m0 + waveM;
        const int bb    = rowg0 >> 11;
        const size_t bhh = (size_t)(bb * NH + hh);

#pragma unroll
        for (int n = 0; n < 4; ++n) {
            int cl = n * 16 + l15;
#pragma unroll
            for (int m = 0; m < 4; ++m) {
#pragma unroll
                for (int r = 0; r < 4; ++r) {
                    float v  = acc[m][n][r];
                    float pv = __shfl_xor(v, 1);
                    int rl = m * 16 + (lhi << 2) + r;
                    if (z == 2) {
                        Ct[cl * 72 + rl] = f2bf(v);
                    } else {
                        int ss = (rowg0 + rl) & (SEQ - 1);
                        float2 cs = tab[(ss << 5) + (cl >> 1)];
                        float o = (cl & 1) ? (pv * cs.y + v * cs.x)
                                           : (v * cs.x - pv * cs.y);
                        if (z == 0) o *= 0.18033688011f;  // (1/8)*log2(e)
                        Ct[rl * 72 + cl] = f2bf(o);
                    }
                }
            }
        }
        asm volatile("s_waitcnt lgkmcnt(0)" ::: "memory");

        const int lr = lane >> 3;
        const int lc = (lane & 7) << 3;
#pragma unroll
        for (int i = 0; i < 8; ++i) {
            int rl = i * 8 + lr;
            uint4 w = *(const uint4*)&Ct[rl * 72 + lc];
            if (z == 2) {
                int ss0 = rowg0 & (SEQ - 1);
                *(uint4*)(Vt + (bhh * DK + rl) * SEQ + ss0 + lc) = w;
            } else {
                int ss = (rowg0 + rl) & (SEQ - 1);
                unsigned short* dst = (z == 0) ? Qh : Kh;
                *(uint4*)(dst + (bhh * SEQ + ss) * DK + lc) = w;
            }
        }
    }
}

// ---------------------------------------------------------------------------
// causal flash attention v8 (R10's EXACT kernel — known-pass):
//  - 512 paired blocks (pi, 31-pi), uniform 33 kv-iters
//  - K/V staged in LDS, 3-buffer, 2-ahead prefetch, vmcnt(4)
//  - both-sides XOR swizzle, cvt_pk P, defer-max, swapped QK
// ---------------------------------------------------------------------------
__global__ __launch_bounds__(256) void attn_kernel(
    const unsigned short* __restrict__ Qh,
    const unsigned short* __restrict__ Kh,
    const unsigned short* __restrict__ Vt,
    unsigned short* __restrict__ O)
{
    __shared__ unsigned short Ks[3][64 * 64];   // 8 KB x3
    __shared__ unsigned short Vs[3][64 * 64];   // 8 KB x3
    __shared__ unsigned short P[4][16 * 64];    // 8 KB

    const int tid  = threadIdx.x;
    const int lane = tid & 63;
    const int wid  = tid >> 6;
    const int l15 = lane & 15, lhi = lane >> 4;

    const int L   = blockIdx.x;
    const int xcd = L & 7;
    const int r0  = L >> 3;              // 0..63
    const int bh  = (xcd << 2) | (r0 & 3);
    const int pi  = r0 >> 2;             // 0..15
    const int b = bh >> 4, h = bh & 15;

    const unsigned short* Qb = Qh + (size_t)bh * SEQ * DK;
    const unsigned short* Kb = Kh + (size_t)bh * SEQ * DK;
    const unsigned short* Vb = Vt + (size_t)bh * DK * SEQ;

    const int NT0 = pi + 1;              // iters in phase 0
    const int NTT = 33;                  // total iters (uniform for all blocks)

    auto kv_of = [&](int g) { return (g < NT0 ? g : g - NT0) << 6; };

    auto STAGE = [&](int buf, int kv0s) {
#pragma unroll
        for (int c = 0; c < 2; ++c) {
            int ub = c * 256 + wid * 64;
            int u  = ub + lane;
            int kr = u >> 3;
            int kc = (u & 7) ^ (kr & 7);
            gload16(Kb + (size_t)(kv0s + kr) * DK + kc * 8, &Ks[buf][(size_t)ub * 8]);
            gload16(Vb + (size_t)kr * SEQ + kv0s + kc * 8, &Vs[buf][(size_t)ub * 8]);
        }
    };

    const f32x4 zero = {0.f, 0.f, 0.f, 0.f};
    const f32x4 ninf = {-1e30f, -1e30f, -1e30f, -1e30f};
    const int sw = l15 & 7;

    STAGE(0, 0);
    STAGE(1, kv_of(1));
    int g = 0;

    for (int ph = 0; ph < 2; ++ph) {
        const int qt = ph ? (31 - pi) : pi;
        const int q0 = qt << 6;
        const int qw = q0 + wid * 16;
        const int lastkt = qt;

        bf16x8 qf[2];
#pragma unroll
        for (int kk = 0; kk < 2; ++kk)
            qf[kk] = *(const bf16x8*)(Qb + (size_t)(qw + l15) * DK + kk * 32 + lhi * 8);

        f32x4 oacc[4];
#pragma unroll
        for (int nd = 0; nd < 4; ++nd) oacc[nd] = zero;
        float mrow = -1e30f;
        float lrow = 0.f;

        for (int kt = 0; kt <= lastkt; ++kt, ++g) {
            const int kv0 = kt << 6;
            const bool diag = (kt == lastkt);
            const int nlim = diag ? (wid + 1) : 4;

            if (g < NTT - 1) asm volatile("s_waitcnt vmcnt(4)" ::: "memory");
            else             asm volatile("s_waitcnt vmcnt(0)" ::: "memory");
            __builtin_amdgcn_s_barrier();
            __builtin_amdgcn_sched_barrier(0);
            if (g + 2 < NTT) STAGE((g + 2) % 3, kv_of(g + 2));

            const unsigned short* Kc = Ks[g % 3];
            const unsigned short* Vc = Vs[g % 3];

            f32x4 s[4];
#pragma unroll
            for (int n = 0; n < 4; ++n) s[n] = (n < nlim) ? zero : ninf;

            __builtin_amdgcn_s_setprio(1);
#pragma unroll
            for (int n = 0; n < 4; ++n) {
                if (n < nlim) {
                    int rr = n * 16 + l15;
                    bf16x8 k0 = *(const bf16x8*)&Kc[rr * 64 + ((lhi ^ sw) << 3)];
                    bf16x8 k1 = *(const bf16x8*)&Kc[rr * 64 + (((4 + lhi) ^ sw) << 3)];
                    s[n] = __builtin_amdgcn_mfma_f32_16x16x32_bf16(k0, qf[0], s[n], 0, 0, 0);
                    s[n] = __builtin_amdgcn_mfma_f32_16x16x32_bf16(k1, qf[1], s[n], 0, 0, 0);
                }
            }
            __builtin_amdgcn_s_setprio(0);

            if (diag) {
                const int qg = qw + l15;
#pragma unroll
                for (int n = 0; n < 4; ++n) {
                    if (n < nlim) {
#pragma unroll
                        for (int rr = 0; rr < 4; ++rr) {
                            int kg = kv0 + n * 16 + (lhi << 2) + rr;
                            if (kg > qg) s[n][rr] = -1e30f;
                        }
                    }
                }
            }

            float mx = fmaxf(fmaxf(s[0][0], s[0][1]), fmaxf(s[0][2], s[0][3]));
#pragma unroll
            for (int n = 1; n < 4; ++n)
                mx = fmaxf(mx, fmaxf(fmaxf(s[n][0], s[n][1]), fmaxf(s[n][2], s[n][3])));
            mx = fmaxf(mx, __shfl_xor(mx, 16));
            mx = fmaxf(mx, __shfl_xor(mx, 32));

            float alpha = 1.f;
            const int allDefer = __all(mx <= mrow + 8.f);
            if (!allDefer) {
                float mn = fmaxf(mrow, mx);
                alpha = __builtin_amdgcn_exp2f(mrow - mn);
                mrow = mn;
            }

#pragma unroll
            for (int n = 0; n < 4; ++n)
#pragma unroll
                for (int rr = 0; rr < 4; ++rr)
                    s[n][rr] = __builtin_amdgcn_exp2f(s[n][rr] - mrow);

            float rs = 0.f;
#pragma unroll
            for (int n = 0; n < 4; ++n)
                rs += (s[n][0] + s[n][1]) + (s[n][2] + s[n][3]);
            rs += __shfl_xor(rs, 16);
            rs += __shfl_xor(rs, 32);
            lrow = allDefer ? (lrow + rs) : (lrow * alpha + rs);

#pragma unroll
            for (int n = 0; n < 4; ++n) {
                uint2 pk;
                pk.x = cvtpk(s[n][0], s[n][1]);
                pk.y = cvtpk(s[n][2], s[n][3]);
                int cW = 2 * n + (lhi >> 1);
                *(uint2*)&P[wid][(l15 << 6) + ((cW ^ sw) << 3) + ((lhi & 1) << 2)] = pk;
            }

            if (!allDefer) {
                float a0 = __shfl(alpha, (lhi << 2) + 0);
                float a1 = __shfl(alpha, (lhi << 2) + 1);
                float a2 = __shfl(alpha, (lhi << 2) + 2);
                float a3 = __shfl(alpha, (lhi << 2) + 3);
#pragma unroll
                for (int nd = 0; nd < 4; ++nd) {
                    oacc[nd][0] *= a0; oacc[nd][1] *= a1;
                    oacc[nd][2] *= a2; oacc[nd][3] *= a3;
                }
            }

            asm volatile("s_waitcnt lgkmcnt(0)" ::: "memory");
            const int kklim = diag ? ((nlim + 1) >> 1) : 2;
            bf16x8 pa[2];
#pragma unroll
            for (int kk = 0; kk < 2; ++kk)
                if (kk < kklim)
                    pa[kk] = *(const bf16x8*)&P[wid][(l15 << 6) + ((((kk << 2) + lhi) ^ sw) << 3)];

            __builtin_amdgcn_s_setprio(1);
#pragma unroll
            for (int nd = 0; nd < 4; ++nd)
#pragma unroll
                for (int kk = 0; kk < 2; ++kk)
                    if (kk < kklim) {
                        int rd = nd * 16 + l15;
                        bf16x8 vf = *(const bf16x8*)&Vc[rd * 64 + ((((kk << 2) + lhi) ^ sw) << 3)];
                        oacc[nd] = __builtin_amdgcn_mfma_f32_16x16x32_bf16(pa[kk], vf, oacc[nd], 0, 0, 0);
                    }
            __builtin_amdgcn_s_setprio(0);
        }

        float inv = 1.f / lrow;
        float i0 = __shfl(inv, (lhi << 2) + 0);
        float i1 = __shfl(inv, (lhi << 2) + 1);
        float i2 = __shfl(inv, (lhi << 2) + 2);
        float i3 = __shfl(inv, (lhi << 2) + 3);
#pragma unroll
        for (int nd = 0; nd < 4; ++nd) {
            int d = nd * 16 + l15;
            int rowb = qw + (lhi << 2);
            O[((size_t)(b * SEQ + rowb + 0)) * D_MODEL + h * DK + d] = f2bf(oacc[nd][0] * i0);
            O[((size_t)(b * SEQ + rowb + 1)) * D_MODEL + h * DK + d] = f2bf(oacc[nd][1] * i1);
            O[((size_t)(b * SEQ + rowb + 2)) * D_MODEL + h * DK + d] = f2bf(oacc[nd][2] * i2);
            O[((size_t)(b * SEQ + rowb + 3)) * D_MODEL + h * DK + d] = f2bf(oacc[nd][3] * i3);
        }
    }
}

// ---------------------------------------------------------------------------
extern "C" void kernel_launch(void* const* d_in, const int* in_sizes, int n_in,
                              void* d_out, int out_size, void* d_ws, size_t ws_size,
                              hipStream_t stream)
{
    const float* x  = (const float*)d_in[0];
    const float* Wq = (const float*)d_in[1];
    const float* Wk = (const float*)d_in[2];
    const float* Wv = (const float*)d_in[3];
    const float* Wo = (const float*)d_in[4];
    float* out = (float*)d_out;

    char* ws = (char*)d_ws;
    unsigned short* xb  = (unsigned short*)(ws);                    // 8 MB (reused as attn buf)
    unsigned short* Wqb = (unsigned short*)(ws + ( 8ull << 20));
    unsigned short* Wkb = (unsigned short*)(ws + (10ull << 20));
    unsigned short* Wvb = (unsigned short*)(ws + (12ull << 20));
    unsigned short* Wob = (unsigned short*)(ws + (14ull << 20));
    unsigned short* Qh  = (unsigned short*)(ws + (16ull << 20));    // [bh][s][64]
    unsigned short* Kh  = (unsigned short*)(ws + (24ull << 20));    // [bh][s][64]
    unsigned short* Vt  = (unsigned short*)(ws + (32ull << 20));    // [bh][64][s]
    float2*         tab = (float2*)(ws + (40ull << 20));            // 512 KB RoPE table
    unsigned short* attn = xb;

    cast5<<<dim3(512, 6), 256, 0, stream>>>(x, Wq, Wk, Wv, Wo, xb, Wqb, Wkb, Wvb, Wob, tab);

    gemm_bt<1, 128, 128><<<768, 256, 0, stream>>>(
        xb, Wqb, Wkb, Wvb, nullptr, Qh, Kh, Vt, tab, NB * SEQ, D_MODEL);

    attn_kernel<<<512, 256, 0, stream>>>(Qh, Kh, Vt, attn);

    gemm_bt<0, 64, 128><<<512, 256, 0, stream>>>(
        attn, Wob, Wob, Wob, out, nullptr, nullptr, nullptr, nullptr, NB * SEQ, D_MODEL);
}